// Round 3
// baseline (357.513 us; speedup 1.0000x reference)
//
#include <hip/hip_runtime.h>

// Problem constants (fixed by setup_inputs)
constexpr int B = 4;
constexpr int N = 768;
constexpr int D = 16;           // per-node embedding dim
constexpr int E = 12288;        // edges per batch
constexpr int NN = N * N;       // 589824 pairs per batch
constexpr int PAIRS = B * NN;   // 2,359,296
constexpr long long EE_FLOATS = (long long)PAIRS * 2 * D;  // 75,497,472
constexpr int RPB = 4;          // rows per block
constexpr int NQ = N * 4;       // float4s per batch of embeddings (3072 = 48 KB)
constexpr int BMW = RPB * N / 32;  // truth bitmap words (96 = 384 B)

__device__ __forceinline__ float dot4(float4 a, float4 b) {
    return a.x * b.x + a.y * b.y + a.z * b.z + a.w * b.w;
}
__device__ __forceinline__ float absdiff4(float4 a, float4 b) {
    return fabsf(a.x - b.x) + fabsf(a.y - b.y) + fabsf(a.z - b.z) + fabsf(a.w - b.w);
}
// lane-varying 4-way select (c is per-lane constant -> cndmask chain)
__device__ __forceinline__ float4 sel4(int c, float4 a0, float4 a1, float4 a2, float4 a3) {
    float4 r = a0;
    if (c == 1) r = a1;
    if (c == 2) r = a2;
    if (c == 3) r = a3;
    return r;
}

// Single fused kernel: EE fill + logits + truth (zeros AND edge scatter).
// One block per 4 consecutive (b,i) rows; grid = 768 = 3 blocks/CU.
//
// Phases:
//  1. Stage batch-b embeddings (48 KB) into LDS; zero the 384 B truth bitmap.
//  2. Edge scan: each block reads batch-b's src[] (49 KB, L2-hot broadcast
//     across the 192 blocks of this batch); edges whose src falls in the
//     block's 4-row range set a bit in the LDS bitmap (atomicOr, idempotent
//     for duplicate edges). Replaces the separate scatter kernel entirely.
//  3. EE store stream: 96 back-to-back iterations (4 rows x 24), LDS-fed,
//     zero global loads -> no vmcnt waits -> store queue stays deep
//     (fillBuffer-equivalent structure; it sustains ~5.7-6.1 TB/s).
//     f = t + k*256; pair j = f>>3, quarter q = f&7 (loop-invariant):
//     q<4 lanes store e_i quarter q from a register; q>=4 lanes read e_j
//     quarter q-4 from LDS (conflict-free: 32 consecutive float4s per wave).
//  4. Tail: logits + truth. 4-lane groups own one j each (lane t&3 holds
//     quarter t&3 of e_j -> consecutive ds_read_b128, conflict-free);
//     butterfly shfl_xor(1,2) reduces dot(e_j,W2) and sum|e_i-e_j|; lane 0
//     of each group writes logits[j] and truth[j] = bitmap bit (16
//     consecutive writers x 4B = full 64B lines).
__global__ __launch_bounds__(256) void fused_all_kernel(
    const float4* __restrict__ emb4, const int* __restrict__ edges,
    const float* __restrict__ W, const float* __restrict__ bias,
    float4* __restrict__ ee4, float* __restrict__ logits,
    float* __restrict__ truth) {
    __shared__ float4 semb[NQ];      // 48 KB
    __shared__ unsigned bm[BMW];     // 384 B

    const int g = blockIdx.x;                    // 0 .. B*N/RPB-1
    const int b = g / (N / RPB);
    const int i0 = (g - b * (N / RPB)) * RPB;
    const int t = threadIdx.x;

    // -- phase 1: stage embeddings + zero bitmap --
    const float4* __restrict__ eb = emb4 + (size_t)b * NQ;
#pragma unroll
    for (int k = 0; k < NQ / 256; ++k)
        semb[t + k * 256] = eb[t + k * 256];
    if (t < BMW) bm[t] = 0u;
    __syncthreads();

    // -- phase 2: edge scan for this block's 4 rows --
    const int* __restrict__ esrc = edges + b * 2 * E;
    const int* __restrict__ edst = esrc + E;
#pragma unroll 1
    for (int e = t; e < E; e += 256) {
        const int s = esrc[e];
        const unsigned rr = (unsigned)(s - i0);
        if (rr < (unsigned)RPB) {
            const int d = edst[e];
            atomicOr(&bm[(rr * N + d) >> 5], 1u << (d & 31));
        }
    }
    __syncthreads();

    // -- phase 3: EE store stream --
    const int q = t & 7;
    const int qq = q & 3;
    const bool isI = (q < 4);
#pragma unroll
    for (int r = 0; r < RPB; ++r) {
        const int i = i0 + r;
        const float4 eiq = semb[i * 4 + qq];
        float4* __restrict__ orow = ee4 + (size_t)(b * N + i) * (N * 8);
#pragma unroll
        for (int k = 0; k < (N * 8) / 256; ++k) {  // 24 iterations
            const int f = t + k * 256;
            float4 v = eiq;
            if (!isI) v = semb[(f >> 3) * 4 + qq];  // LDS only -- no vmcnt
            orow[f] = v;                            // fire-and-forget
        }
    }

    // -- phase 4: logits + truth tail --
    const float4* __restrict__ W4 = (const float4*)W;  // 8 float4 = 32 weights
    const float4 wa0 = W4[0], wa1 = W4[1], wa2 = W4[2], wa3 = W4[3];
    const int ql = t & 3;
    const int gsub = t >> 2;                     // 0..63: j within pass
    const bool wr = (ql == 0);
    const float4 myWb = sel4(ql, W4[4], W4[5], W4[6], W4[7]);
    const float bb = bias[0];

#pragma unroll 1
    for (int r = 0; r < RPB; ++r) {
        const int i = i0 + r;
        const float4 e0 = semb[i * 4 + 0], e1 = semb[i * 4 + 1];
        const float4 e2 = semb[i * 4 + 2], e3 = semb[i * 4 + 3];
        const float base =
            dot4(e0, wa0) + dot4(e1, wa1) + dot4(e2, wa2) + dot4(e3, wa3) + bb;
        const float4 myEi = sel4(ql, e0, e1, e2, e3);
        float* __restrict__ lrow = logits + (size_t)(b * N + i) * N;
        float* __restrict__ trow = truth + (size_t)(b * N + i) * N;
#pragma unroll
        for (int p = 0; p < N / 64; ++p) {       // 12 passes
            const int j = p * 64 + gsub;
            const float4 c = semb[j * 4 + ql];   // consecutive -> conflict-free
            float pa = dot4(c, myWb);
            float pd = absdiff4(myEi, c);
            pa += __shfl_xor(pa, 1, 64);
            pd += __shfl_xor(pd, 1, 64);
            pa += __shfl_xor(pa, 2, 64);
            pd += __shfl_xor(pd, 2, 64);
            if (wr) {
                lrow[j] = (pd != 0.f) ? (base + pa) : -10.0f;
                const unsigned bits = bm[(r * N + j) >> 5];
                trow[j] = ((bits >> (j & 31)) & 1u) ? 1.0f : 0.0f;
            }
        }
    }
}

extern "C" void kernel_launch(void* const* d_in, const int* in_sizes, int n_in,
                              void* d_out, int out_size, void* d_ws, size_t ws_size,
                              hipStream_t stream) {
    const float4* emb4 = (const float4*)d_in[0];  // [B,N,D] fp32 -> 4 float4/node
    const int* edges = (const int*)d_in[1];       // [B,2,E] int32
    const float* W = (const float*)d_in[2];       // [2D]
    const float* bias = (const float*)d_in[3];    // [1]

    float* out = (float*)d_out;
    float* ee = out;
    float* logits = out + EE_FLOATS;
    float* truth = out + EE_FLOATS + (long long)PAIRS;

    // Single dispatch: 768 blocks = 3 blocks/CU (48.4 KB LDS fits 3x in 160 KB)
    fused_all_kernel<<<B * N / RPB, 256, 0, stream>>>(
        emb4, edges, W, bias, (float4*)ee, logits, truth);
}

// Round 5
// 328.340 us; speedup vs baseline: 1.0889x; 1.0889x over previous
//
#include <hip/hip_runtime.h>

// Problem constants (fixed by setup_inputs)
constexpr int B = 4;
constexpr int N = 768;
constexpr int D = 16;           // per-node embedding dim
constexpr int E = 12288;        // edges per batch
constexpr int NN = N * N;       // 589824 pairs per batch
constexpr int PAIRS = B * NN;   // 2,359,296
// d_out layout (fp32, concatenated in return order):
//   [0, B*NN*2D)                      edge_embeddings
//   [B*NN*2D, B*NN*2D + B*NN)         logits
//   [.. + B*NN, .. + 2*B*NN)          truth
constexpr long long EE_FLOATS = (long long)PAIRS * 2 * D;  // 75,497,472

// native clang vector type: bit-identical to float4, accepted by
// __builtin_nontemporal_store (HIP_vector_type is a struct and is rejected)
typedef float floatx4 __attribute__((ext_vector_type(4)));

__device__ __forceinline__ float dot4(float4 a, float4 b) {
    return a.x * b.x + a.y * b.y + a.z * b.z + a.w * b.w;
}
__device__ __forceinline__ float absdiff4(float4 a, float4 b) {
    return fabsf(a.x - b.x) + fabsf(a.y - b.y) + fabsf(a.z - b.z) + fabsf(a.w - b.w);
}

// Fused EE fill + logits + truth-zero: one block per (b,i) row (R1 structure,
// best normalized residual of rounds 0-3). One change vs R1: the 302 MB EE
// stream uses NON-TEMPORAL stores ('nt' bit). The stream is 9.4x L2 capacity
// and never re-read in-kernel; plain stores force continuous L2 allocate/
// evict/writeback churn. nt stores bypass L2 allocation -> tests whether L2
// write churn is why the stream runs at ~2.9 TB/s while fillBuffer hits 6.1.
//
// Main loop (24 iters): float4 f = t + k*256 in the row's 6144; pair j=f>>3,
// quarter q=f&7 (loop-invariant since 256 % 8 == 0):
//   q<4  lanes: e_i quarter q, held in a register -> pure stores
//   q>=4 lanes: e_j quarter q-4, coalesced L2-hot load, 24-deep unrolled ILP
// Per-wave store = 64 x 16B = 1 KiB contiguous.
__global__ __launch_bounds__(256) void row_fused_kernel(
    const float4* __restrict__ emb4, const float* __restrict__ W,
    const float* __restrict__ bias, float4* __restrict__ ee4,
    float* __restrict__ logits, float* __restrict__ truth) {
    const int row = blockIdx.x;          // = b*N + i
    const int b = row / N;
    const int i = row - b * N;
    const float4* __restrict__ eb = emb4 + (size_t)b * N * 4;  // 4 float4/node
    const float4* __restrict__ ei = eb + i * 4;

    const int t = threadIdx.x;
    const int q = t & 7;
    const int qq = q & 3;
    const bool isI = (q < 4);
    const float4 eiq = ei[qq];           // broadcast; used by q<4 lanes

    floatx4* __restrict__ orow = (floatx4*)(ee4 + (size_t)row * (N * 8));
#pragma unroll
    for (int k = 0; k < (N * 8) / 256; ++k) {   // 24 iterations
        const int f = t + k * 256;
        float4 v = eiq;
        if (!isI) v = eb[(f >> 3) * 4 + qq];
        floatx4 nv = {v.x, v.y, v.z, v.w};
        __builtin_nontemporal_store(nv, orow + f);   // 'nt' streaming store
    }

    // ---- logits + truth zeroing for this row ----
    const float4* __restrict__ W4 = (const float4*)W;  // 8 float4 = 32 weights
    const float4 wa0 = W4[0], wa1 = W4[1], wa2 = W4[2], wa3 = W4[3];
    const float4 wb0 = W4[4], wb1 = W4[5], wb2 = W4[6], wb3 = W4[7];
    const float4 e0 = ei[0], e1 = ei[1], e2 = ei[2], e3 = ei[3];
    const float base =
        dot4(e0, wa0) + dot4(e1, wa1) + dot4(e2, wa2) + dot4(e3, wa3) + bias[0];
    float* __restrict__ lrow = logits + (size_t)row * N;
    float* __restrict__ trow = truth + (size_t)row * N;
#pragma unroll
    for (int k = 0; k < N / 256; ++k) {          // 3 iterations
        const int j = t + k * 256;
        const float4* __restrict__ ej = eb + j * 4;
        const float4 c0 = ej[0], c1 = ej[1], c2 = ej[2], c3 = ej[3];
        const float acc = base + dot4(c0, wb0) + dot4(c1, wb1) +
                          dot4(c2, wb2) + dot4(c3, wb3);
        const float diff = absdiff4(e0, c0) + absdiff4(e1, c1) +
                           absdiff4(e2, c2) + absdiff4(e3, c3);
        lrow[j] = (diff != 0.f) ? acc : -10.0f;
        trow[j] = 0.0f;   // plain store: scatter kernel re-touches these lines
    }
}

// Edge scatter into truth. Duplicates idempotent (plain store of 1.0).
// Runs after row_fused_kernel's zeroing (same stream => ordered).
__global__ void truth_scatter_kernel(const int* __restrict__ edges,
                                     float* __restrict__ truth) {
    int tid = blockIdx.x * blockDim.x + threadIdx.x;
    if (tid >= B * E) return;
    int b = tid / E;
    int e = tid - b * E;
    int src = edges[b * 2 * E + e];
    int dst = edges[b * 2 * E + E + e];
    truth[(size_t)b * NN + src * N + dst] = 1.0f;
}

extern "C" void kernel_launch(void* const* d_in, const int* in_sizes, int n_in,
                              void* d_out, int out_size, void* d_ws, size_t ws_size,
                              hipStream_t stream) {
    const float4* emb4 = (const float4*)d_in[0];  // [B,N,D] fp32 -> 4 float4/node
    const int* edges = (const int*)d_in[1];       // [B,2,E]
    const float* W = (const float*)d_in[2];       // [2D]
    const float* bias = (const float*)d_in[3];    // [1]

    float* out = (float*)d_out;
    float* ee = out;
    float* logits = out + EE_FLOATS;
    float* truth = out + EE_FLOATS + (long long)PAIRS;

    row_fused_kernel<<<B * N, 256, 0, stream>>>(emb4, W, bias, (float4*)ee,
                                                logits, truth);
    truth_scatter_kernel<<<(B * E + 255) / 256, 256, 0, stream>>>(edges, truth);
}